// Round 1
// baseline (5009.626 us; speedup 1.0000x reference)
//
#include <hip/hip_runtime.h>
#include <math.h>

// Problem constants (Qwen3-MoE layer, B=2 S=1024 D=2048 H=16 KVH=4 HD=128 E=64 K=8 F=768)
#define NB     2
#define SEQ    1024
#define TOKS   2048      // B*S
#define DMODEL 2048
#define NH     16
#define NKV    4
#define HDIM   128
#define NEXP   64
#define TOPK   8
#define FFD    768

// ---------------- rmsnorm over D=2048 (block per token) ----------------
__global__ __launch_bounds__(256) void rmsnorm2048_kernel(const float* __restrict__ x,
                                                          const float* __restrict__ w,
                                                          float* __restrict__ out) {
    int t = blockIdx.x;
    const float* xr = x + (size_t)t * DMODEL;
    float* orow = out + (size_t)t * DMODEL;
    int tid = threadIdx.x;
    float4 a = ((const float4*)xr)[tid * 2];
    float4 b = ((const float4*)xr)[tid * 2 + 1];
    float ss = a.x*a.x + a.y*a.y + a.z*a.z + a.w*a.w
             + b.x*b.x + b.y*b.y + b.z*b.z + b.w*b.w;
    __shared__ float red[256];
    red[tid] = ss;
    __syncthreads();
    for (int s = 128; s > 0; s >>= 1) {
        if (tid < s) red[tid] += red[tid + s];
        __syncthreads();
    }
    float rs = rsqrtf(red[0] * (1.0f / DMODEL) + 1e-6f);
    float4 w0 = ((const float4*)w)[tid * 2];
    float4 w1 = ((const float4*)w)[tid * 2 + 1];
    float4 o0, o1;
    o0.x = a.x * rs * w0.x; o0.y = a.y * rs * w0.y; o0.z = a.z * rs * w0.z; o0.w = a.w * rs * w0.w;
    o1.x = b.x * rs * w1.x; o1.y = b.y * rs * w1.y; o1.z = b.z * rs * w1.z; o1.w = b.w * rs * w1.w;
    ((float4*)orow)[tid * 2] = o0;
    ((float4*)orow)[tid * 2 + 1] = o1;
}

// ---------------- generic f32 GEMM: C = A[M,K] @ B[K,N] (+resid), 128x128x16 tile ----------------
__global__ __launch_bounds__(256) void gemm128_kernel(const float* __restrict__ A,
                                                      const float* __restrict__ Bm,
                                                      const float* __restrict__ resid,
                                                      float* __restrict__ C,
                                                      int M, int N, int K) {
    __shared__ float As[16][132];  // As[k][m], stride 132 keeps 16B alignment for b128 reads
    __shared__ float Bs[16][132];  // Bs[k][n]
    int tid = threadIdx.x;
    int bm = blockIdx.y * 128, bn = blockIdx.x * 128;
    int tx = tid & 15, ty = tid >> 4;
    float acc[8][8];
#pragma unroll
    for (int i = 0; i < 8; ++i)
#pragma unroll
        for (int j = 0; j < 8; ++j) acc[i][j] = 0.f;

    int arow = tid >> 1, acol = (tid & 1) * 8;      // A tile: 128 rows x 16 k
    int brow = tid >> 4, bcol = (tid & 15) * 8;     // B tile: 16 k x 128 cols
    const float* Aptr = A + (size_t)(bm + arow) * K + acol;
    const float* Bptr = Bm + (size_t)brow * N + bn + bcol;

    for (int k0 = 0; k0 < K; k0 += 16) {
        float4 a0 = *(const float4*)(Aptr + k0);
        float4 a1 = *(const float4*)(Aptr + k0 + 4);
        As[acol + 0][arow] = a0.x; As[acol + 1][arow] = a0.y;
        As[acol + 2][arow] = a0.z; As[acol + 3][arow] = a0.w;
        As[acol + 4][arow] = a1.x; As[acol + 5][arow] = a1.y;
        As[acol + 6][arow] = a1.z; As[acol + 7][arow] = a1.w;
        const float* bp = Bptr + (size_t)k0 * N;
        *(float4*)&Bs[brow][bcol]     = *(const float4*)bp;
        *(float4*)&Bs[brow][bcol + 4] = *(const float4*)(bp + 4);
        __syncthreads();
#pragma unroll
        for (int k = 0; k < 16; ++k) {
            float a[8], b[8];
#pragma unroll
            for (int i = 0; i < 8; ++i) a[i] = As[k][ty * 8 + i];
#pragma unroll
            for (int j = 0; j < 8; ++j) b[j] = Bs[k][tx * 8 + j];
#pragma unroll
            for (int i = 0; i < 8; ++i)
#pragma unroll
                for (int j = 0; j < 8; ++j) acc[i][j] += a[i] * b[j];
        }
        __syncthreads();
    }
#pragma unroll
    for (int i = 0; i < 8; ++i) {
        size_t rowoff = (size_t)(bm + ty * 8 + i) * N + bn + tx * 8;
        float4 c0 = make_float4(acc[i][0], acc[i][1], acc[i][2], acc[i][3]);
        float4 c1 = make_float4(acc[i][4], acc[i][5], acc[i][6], acc[i][7]);
        if (resid) {
            float4 r0 = *(const float4*)(resid + rowoff);
            float4 r1 = *(const float4*)(resid + rowoff + 4);
            c0.x += r0.x; c0.y += r0.y; c0.z += r0.z; c0.w += r0.w;
            c1.x += r1.x; c1.y += r1.y; c1.z += r1.z; c1.w += r1.w;
        }
        *(float4*)(C + rowoff) = c0;
        *(float4*)(C + rowoff + 4) = c1;
    }
}

// ---------------- per-head q/k rmsnorm + RoPE, in place ----------------
__global__ __launch_bounds__(128) void qknorm_rope_kernel(float* __restrict__ q, float* __restrict__ kbuf,
                                                          const float* __restrict__ qn_w,
                                                          const float* __restrict__ kn_w,
                                                          const float* __restrict__ cosb,
                                                          const float* __restrict__ sinb) {
    int t = blockIdx.x;      // token
    int head = blockIdx.y;   // 0..15 q heads, 16..19 k heads
    int d = threadIdx.x;     // 0..127
    float* buf; const float* w;
    if (head < NH) { buf = q + ((size_t)t * NH + head) * HDIM; w = qn_w; }
    else           { buf = kbuf + ((size_t)t * NKV + (head - NH)) * HDIM; w = kn_w; }
    float v = buf[d];
    __shared__ float red[128];
    __shared__ float nb[128];
    red[d] = v * v;
    __syncthreads();
    for (int s = 64; s > 0; s >>= 1) { if (d < s) red[d] += red[d + s]; __syncthreads(); }
    float rs = rsqrtf(red[0] * (1.0f / HDIM) + 1e-6f);
    float n = v * rs * w[d];
    nb[d] = n;
    __syncthreads();
    float rh = (d < 64) ? -nb[d + 64] : nb[d - 64];
    float c  = cosb[(size_t)t * HDIM + d];
    float s2 = sinb[(size_t)t * HDIM + d];
    buf[d] = n * c + rh * s2;
}

// ---------------- flash attention (causal, GQA 16q/4kv), block = (b,h, 32 q rows) ----------------
__global__ __launch_bounds__(256) void attn_kernel(const float* __restrict__ q,
                                                   const float* __restrict__ kb,
                                                   const float* __restrict__ vb,
                                                   float* __restrict__ o) {
    int bh = blockIdx.x;            // b*16+h
    int b = bh >> 4, hh = bh & 15;
    int kvh = hh >> 2;
    int qt = blockIdx.y;            // q tile, 32 rows
    int m0 = qt * 32;
    int tid = threadIdx.x;
    __shared__ float Qs[32][132];
    __shared__ float Ks[32][132];
    __shared__ float Vs[32][132];
    __shared__ float Ss[32][33];
    __shared__ float rowm[32], rowl[32], rowa[32];
    const float scale = 0.08838834764831845f;  // 1/sqrt(128)

    int lr = tid >> 3, lc = (tid & 7) * 16;
    {
        const float* src = q + (((size_t)(b * SEQ + m0 + lr)) * NH + hh) * HDIM + lc;
#pragma unroll
        for (int p = 0; p < 4; ++p) {
            float4 v4 = *(const float4*)(src + p * 4);
            Qs[lr][lc + p * 4 + 0] = v4.x * scale;
            Qs[lr][lc + p * 4 + 1] = v4.y * scale;
            Qs[lr][lc + p * 4 + 2] = v4.z * scale;
            Qs[lr][lc + p * 4 + 3] = v4.w * scale;
        }
    }
    if (tid < 32) { rowm[tid] = -1e30f; rowl[tid] = 0.f; }
    float oacc[16];
#pragma unroll
    for (int j = 0; j < 16; ++j) oacc[j] = 0.f;
    int mrow = tid & 31, dbase = (tid >> 5) * 16;
    int mi = tid >> 3, kbase = (tid & 7) * 4;
    __syncthreads();

    for (int kt = 0; kt <= qt; ++kt) {
        int k0 = kt * 32;
        {
            const float* ksrc = kb + (((size_t)(b * SEQ + k0 + lr)) * NKV + kvh) * HDIM + lc;
            const float* vsrc = vb + (((size_t)(b * SEQ + k0 + lr)) * NKV + kvh) * HDIM + lc;
#pragma unroll
            for (int p = 0; p < 4; ++p) {
                *(float4*)&Ks[lr][lc + p * 4] = *(const float4*)(ksrc + p * 4);
                *(float4*)&Vs[lr][lc + p * 4] = *(const float4*)(vsrc + p * 4);
            }
        }
        __syncthreads();
        // scores: thread -> (mi, 4 keys)
        float sc[4] = {0.f, 0.f, 0.f, 0.f};
#pragma unroll 8
        for (int d4 = 0; d4 < 32; ++d4) {
            float4 qv = *(const float4*)&Qs[mi][d4 * 4];
#pragma unroll
            for (int i = 0; i < 4; ++i) {
                float4 kv = *(const float4*)&Ks[kbase + i][d4 * 4];
                sc[i] += qv.x * kv.x + qv.y * kv.y + qv.z * kv.z + qv.w * kv.w;
            }
        }
#pragma unroll
        for (int i = 0; i < 4; ++i) {
            int kg = k0 + kbase + i;
            Ss[mi][kbase + i] = (kg <= m0 + mi) ? sc[i] : -1e30f;
        }
        __syncthreads();
        if (tid < 32) {
            float mold = rowm[tid];
            float tm = mold;
            for (int j = 0; j < 32; ++j) tm = fmaxf(tm, Ss[tid][j]);
            float al = __expf(mold - tm);
            float sum = 0.f;
            for (int j = 0; j < 32; ++j) {
                float p = __expf(Ss[tid][j] - tm);
                Ss[tid][j] = p;
                sum += p;
            }
            rowa[tid] = al; rowm[tid] = tm;
            rowl[tid] = rowl[tid] * al + sum;
        }
        __syncthreads();
        float al = rowa[mrow];
#pragma unroll
        for (int j = 0; j < 16; ++j) oacc[j] *= al;
        for (int kk = 0; kk < 32; ++kk) {
            float p = Ss[mrow][kk];
            const float* vrow = &Vs[kk][dbase];
#pragma unroll
            for (int j = 0; j < 16; ++j) oacc[j] += p * vrow[j];
        }
        __syncthreads();
    }
    float linv = 1.0f / rowl[mrow];
    float* dst = o + ((size_t)(b * SEQ + m0 + mrow)) * DMODEL + hh * HDIM + dbase;
#pragma unroll
    for (int p = 0; p < 4; ++p) {
        float4 v4 = make_float4(oacc[p * 4 + 0] * linv, oacc[p * 4 + 1] * linv,
                                oacc[p * 4 + 2] * linv, oacc[p * 4 + 3] * linv);
        *(float4*)(dst + p * 4) = v4;
    }
}

// ---------------- router logits: block per token, thread per expert ----------------
__global__ __launch_bounds__(64) void router_kernel(const float* __restrict__ ht,
                                                    const float* __restrict__ rw,
                                                    float* __restrict__ logits) {
    int t = blockIdx.x; int e = threadIdx.x;
    const float* hrow = ht + (size_t)t * DMODEL;
    float acc = 0.f;
    for (int d = 0; d < DMODEL; ++d) acc = fmaf(hrow[d], rw[(size_t)d * NEXP + e], acc);
    logits[(size_t)t * NEXP + e] = acc;
}

// ---------------- top-8 in logit space (softmax Z cancels after renorm) ----------------
__global__ __launch_bounds__(64) void topk_kernel(const float* __restrict__ logits,
                                                  float* __restrict__ topw,
                                                  int* __restrict__ topi) {
    int t = blockIdx.x; int lane = threadIdx.x;
    float v = logits[(size_t)t * NEXP + lane];
    float mx = v;
#pragma unroll
    for (int off = 32; off; off >>= 1) mx = fmaxf(mx, __shfl_xor(mx, off));
    float myv = v;
    float sel_v[TOPK]; int sel_i[TOPK];
#pragma unroll
    for (int it = 0; it < TOPK; ++it) {
        float bv = myv; int bi = lane;
#pragma unroll
        for (int off = 32; off; off >>= 1) {
            float ov = __shfl_xor(bv, off);
            int oi = __shfl_xor(bi, off);
            if (ov > bv || (ov == bv && oi < bi)) { bv = ov; bi = oi; }
        }
        sel_v[it] = bv; sel_i[it] = bi;
        if (lane == bi) myv = -3e38f;
    }
    float sum = 0.f;
#pragma unroll
    for (int it = 0; it < TOPK; ++it) sum += __expf(sel_v[it] - mx);
    if (lane == 0) {
#pragma unroll
        for (int it = 0; it < TOPK; ++it) {
            topw[(size_t)t * TOPK + it] = __expf(sel_v[it] - mx) / sum;
            topi[(size_t)t * TOPK + it] = sel_i[it];
        }
    }
}

// ---------------- routing bookkeeping ----------------
__global__ void zero_small_kernel(int* cnt, int* pos) {
    int i = threadIdx.x;
    if (i < NEXP) { cnt[i] = 0; pos[i] = 0; }
}
__global__ void hist_kernel(const int* __restrict__ topi, int* __restrict__ cnt) {
    int i = blockIdx.x * 256 + threadIdx.x;
    if (i < TOKS * TOPK) atomicAdd(&cnt[topi[i]], 1);
}
__global__ void scan_kernel(const int* __restrict__ cnt, int* __restrict__ eoff) {
    if (threadIdx.x == 0) {
        int a = 0;
        for (int e = 0; e < NEXP; ++e) { eoff[e] = a; a += cnt[e]; }
    }
}
__global__ void scatter_kernel(const int* __restrict__ topi, const float* __restrict__ topw,
                               const int* __restrict__ eoff, int* __restrict__ pos,
                               int* __restrict__ tokl, float* __restrict__ wtl) {
    int i = blockIdx.x * 256 + threadIdx.x;
    if (i >= TOKS * TOPK) return;
    int e = topi[i];
    int slot = atomicAdd(&pos[e], 1);
    int idx = eoff[e] + slot;
    tokl[idx] = i >> 3;          // token id
    wtl[idx] = topw[i];
}

// ---------------- MoE phase A: act[p,f] = silu(ht@wg) * (ht@wu) * wt, 64x64 tile ----------------
__global__ __launch_bounds__(256) void moe_gateup_kernel(const float* __restrict__ ht,
                                                         const float* __restrict__ wg,
                                                         const float* __restrict__ wu,
                                                         const int* __restrict__ tokl,
                                                         const float* __restrict__ wtl,
                                                         const int* __restrict__ eoff,
                                                         const int* __restrict__ ecnt,
                                                         float* __restrict__ act) {
    int e = blockIdx.x, ft = blockIdx.y, mt = blockIdx.z;
    int ne = ecnt[e];
    int r0 = mt * 64;
    if (r0 >= ne) return;
    int base = eoff[e];
    int tid = threadIdx.x;
    __shared__ float As[16][68];
    __shared__ float Gs[16][64];
    __shared__ float Us[16][64];
    int arow = tid >> 2, acol = (tid & 3) * 4;
    int grow = r0 + arow;
    const float* asrc = (grow < ne) ? (ht + (size_t)tokl[base + grow] * DMODEL) : nullptr;
    int wrow = tid >> 4, wcol = (tid & 15) * 4;
    const float* wgp = wg + (size_t)e * DMODEL * FFD + (size_t)ft * 64;
    const float* wup = wu + (size_t)e * DMODEL * FFD + (size_t)ft * 64;
    int tx = tid & 15, ty = tid >> 4;
    float aG[4][4], aU[4][4];
#pragma unroll
    for (int i = 0; i < 4; ++i)
#pragma unroll
        for (int j = 0; j < 4; ++j) { aG[i][j] = 0.f; aU[i][j] = 0.f; }

    for (int k0 = 0; k0 < DMODEL; k0 += 16) {
        float4 av = asrc ? *(const float4*)(asrc + k0 + acol) : make_float4(0.f, 0.f, 0.f, 0.f);
        As[acol + 0][arow] = av.x; As[acol + 1][arow] = av.y;
        As[acol + 2][arow] = av.z; As[acol + 3][arow] = av.w;
        *(float4*)&Gs[wrow][wcol] = *(const float4*)(wgp + (size_t)(k0 + wrow) * FFD + wcol);
        *(float4*)&Us[wrow][wcol] = *(const float4*)(wup + (size_t)(k0 + wrow) * FFD + wcol);
        __syncthreads();
#pragma unroll
        for (int k = 0; k < 16; ++k) {
            float a[4], g[4], u[4];
#pragma unroll
            for (int i = 0; i < 4; ++i) a[i] = As[k][ty * 4 + i];
#pragma unroll
            for (int j = 0; j < 4; ++j) { g[j] = Gs[k][tx * 4 + j]; u[j] = Us[k][tx * 4 + j]; }
#pragma unroll
            for (int i = 0; i < 4; ++i)
#pragma unroll
                for (int j = 0; j < 4; ++j) {
                    aG[i][j] += a[i] * g[j];
                    aU[i][j] += a[i] * u[j];
                }
        }
        __syncthreads();
    }
#pragma unroll
    for (int i = 0; i < 4; ++i) {
        int gr = r0 + ty * 4 + i;
        if (gr < ne) {
            float wt = wtl[base + gr];
            float* dst = act + (size_t)(base + gr) * FFD + ft * 64 + tx * 4;
#pragma unroll
            for (int j = 0; j < 4; ++j) {
                float g = aG[i][j];
                float sg = g / (1.f + __expf(-g));
                dst[j] = sg * aU[i][j] * wt;
            }
        }
    }
}

// ---------------- MoE phase B: out[tok] += act @ wd, 64x64 tile, atomic scatter ----------------
__global__ __launch_bounds__(256) void moe_down_kernel(const float* __restrict__ act,
                                                       const float* __restrict__ wd,
                                                       const int* __restrict__ tokl,
                                                       const int* __restrict__ eoff,
                                                       const int* __restrict__ ecnt,
                                                       float* __restrict__ out) {
    int e = blockIdx.x, dt = blockIdx.y, mt = blockIdx.z;
    int ne = ecnt[e];
    int r0 = mt * 64;
    if (r0 >= ne) return;
    int base = eoff[e];
    int tid = threadIdx.x;
    __shared__ float As[16][68];
    __shared__ float Ws[16][64];
    int arow = tid >> 2, acol = (tid & 3) * 4;
    int grow = r0 + arow;
    const float* asrc = (grow < ne) ? (act + (size_t)(base + grow) * FFD) : nullptr;
    int wrow = tid >> 4, wcol = (tid & 15) * 4;
    const float* wdp = wd + (size_t)e * FFD * DMODEL + (size_t)dt * 64;
    int tx = tid & 15, ty = tid >> 4;
    float acc[4][4];
#pragma unroll
    for (int i = 0; i < 4; ++i)
#pragma unroll
        for (int j = 0; j < 4; ++j) acc[i][j] = 0.f;

    for (int k0 = 0; k0 < FFD; k0 += 16) {
        float4 av = asrc ? *(const float4*)(asrc + k0 + acol) : make_float4(0.f, 0.f, 0.f, 0.f);
        As[acol + 0][arow] = av.x; As[acol + 1][arow] = av.y;
        As[acol + 2][arow] = av.z; As[acol + 3][arow] = av.w;
        *(float4*)&Ws[wrow][wcol] = *(const float4*)(wdp + (size_t)(k0 + wrow) * DMODEL + wcol);
        __syncthreads();
#pragma unroll
        for (int k = 0; k < 16; ++k) {
            float a[4], b[4];
#pragma unroll
            for (int i = 0; i < 4; ++i) a[i] = As[k][ty * 4 + i];
#pragma unroll
            for (int j = 0; j < 4; ++j) b[j] = Ws[k][tx * 4 + j];
#pragma unroll
            for (int i = 0; i < 4; ++i)
#pragma unroll
                for (int j = 0; j < 4; ++j) acc[i][j] += a[i] * b[j];
        }
        __syncthreads();
    }
#pragma unroll
    for (int i = 0; i < 4; ++i) {
        int gr = r0 + ty * 4 + i;
        if (gr < ne) {
            int tok = tokl[base + gr];
            float* dst = out + (size_t)tok * DMODEL + dt * 64 + tx * 4;
#pragma unroll
            for (int j = 0; j < 4; ++j) atomicAdd(dst + j, acc[i][j]);
        }
    }
}

extern "C" void kernel_launch(void* const* d_in, const int* in_sizes, int n_in,
                              void* d_out, int out_size, void* d_ws, size_t ws_size,
                              hipStream_t stream) {
    const float* x    = (const float*)d_in[0];
    const float* cosb = (const float*)d_in[1];
    const float* sinb = (const float*)d_in[2];
    const float* ln1  = (const float*)d_in[3];
    const float* wq   = (const float*)d_in[4];
    const float* wk   = (const float*)d_in[5];
    const float* wv   = (const float*)d_in[6];
    const float* wo   = (const float*)d_in[7];
    const float* qnw  = (const float*)d_in[8];
    const float* knw  = (const float*)d_in[9];
    const float* ln2  = (const float*)d_in[10];
    const float* rw   = (const float*)d_in[11];
    const float* wg   = (const float*)d_in[12];
    const float* wu   = (const float*)d_in[13];
    const float* wd   = (const float*)d_in[14];
    float* out = (float*)d_out;

    // workspace layout (floats); total ~93 MB
    float* ws     = (float*)d_ws;
    float* h      = ws;                       // 4194304  (rmsnorm1 out; reused as attn_o)
    float* qb     = h + 4194304;              // 4194304  (q; reused as ht)
    float* kbuf   = qb + 4194304;             // 1048576
    float* vbuf   = kbuf + 1048576;           // 1048576
    float* act    = vbuf + 1048576;           // 12582912 (16384 x 768)
    float* logits = act + 12582912;           // 131072
    float* topw   = logits + 131072;          // 16384
    float* wtl    = topw + 16384;             // 16384
    int* topi     = (int*)(wtl + 16384);      // 16384
    int* tokl     = topi + 16384;             // 16384
    int* cnt      = tokl + 16384;             // 64
    int* eoff     = cnt + 64;                 // 64
    int* pos      = eoff + 64;                // 64
    float* attn_o = h;                        // alias: h dead after QKV gemms
    float* ht     = qb;                       // alias: q dead after attention

    rmsnorm2048_kernel<<<TOKS, 256, 0, stream>>>(x, ln1, h);
    gemm128_kernel<<<dim3(16, 16), 256, 0, stream>>>(h, wq, nullptr, qb, TOKS, 2048, DMODEL);
    gemm128_kernel<<<dim3(4, 16), 256, 0, stream>>>(h, wk, nullptr, kbuf, TOKS, 512, DMODEL);
    gemm128_kernel<<<dim3(4, 16), 256, 0, stream>>>(h, wv, nullptr, vbuf, TOKS, 512, DMODEL);
    qknorm_rope_kernel<<<dim3(TOKS, NH + NKV), 128, 0, stream>>>(qb, kbuf, qnw, knw, cosb, sinb);
    attn_kernel<<<dim3(NB * NH, SEQ / 32), 256, 0, stream>>>(qb, kbuf, vbuf, attn_o);
    gemm128_kernel<<<dim3(16, 16), 256, 0, stream>>>(attn_o, wo, x, out, TOKS, 2048, DMODEL);
    rmsnorm2048_kernel<<<TOKS, 256, 0, stream>>>(out, ln2, ht);
    router_kernel<<<TOKS, 64, 0, stream>>>(ht, rw, logits);
    topk_kernel<<<TOKS, 64, 0, stream>>>(logits, topw, topi);
    zero_small_kernel<<<1, 64, 0, stream>>>(cnt, pos);
    hist_kernel<<<64, 256, 0, stream>>>(topi, cnt);
    scan_kernel<<<1, 1, 0, stream>>>(cnt, eoff);
    scatter_kernel<<<64, 256, 0, stream>>>(topi, topw, eoff, pos, tokl, wtl);
    moe_gateup_kernel<<<dim3(NEXP, FFD / 64, 32), 256, 0, stream>>>(ht, wg, wu, tokl, wtl, eoff, cnt, act);
    moe_down_kernel<<<dim3(NEXP, DMODEL / 64, 32), 256, 0, stream>>>(act, wd, tokl, eoff, cnt, out);
}